// Round 1
// 683.553 us; speedup vs baseline: 1.2501x; 1.2501x over previous
//
#include <hip/hip_runtime.h>

// LSTM I=16, H=32, B=8192, T=512, fp32 — MFMA version, 8-wave gate-split.
//
// Group = 16 batch rows, handled by ONE block of 512 threads (8 waves).
// Wave wv computes ONE gate N-block: gate g = wv&3 (i,f,g,o), unit half
// uh = wv>>2 (units uh*16..uh*16+15). 9 MFMAs per wave per timestep, in the
// EXACT accumulation order of the 2-wave version (bit-identical gates).
// Gate pre-activations are exchanged through LDS (gbuf, f32, +1 pad col),
// then each lane owns exactly ONE cell element (512 elems / 512 lanes):
// 4x less transcendental work per lane than before. h is re-published via
// the split-bf16 double-buffered planes as before. Two __syncthreads/step.
//
// Rationale vs previous kernel: occupancy was 1 wave/SIMD (10%) with
// VALUBusy+MfmaUtil ~55% -> latency-bound. This gives 4 waves/SIMD
// (16 waves/CU from 2 blocks) so dependency/barrier latency is hidden.
//
// Precision: split-bf16 everywhere, identical term set and order:
// gates = x1@W1 + x2@W1 + x1@W2 (ih) + h1@W1 + h2@W1 + h1@W2 (hh).
// MFMA: v_mfma_f32_16x16x16_bf16 (gfx90a _1k builtin, short4 operands).
//   A: lane holds A[m=lane&15][k=(lane>>4)*4+j]   (j=0..3)
//   B: lane holds B[k=(lane>>4)*4+j][n=lane&15]
//   C/D: lane holds D[row=(lane>>4)*4+reg][col=lane&15]   (verified m89)

typedef short short4v __attribute__((ext_vector_type(4)));
typedef __bf16 bf4 __attribute__((ext_vector_type(4)));
typedef float f4 __attribute__((ext_vector_type(4)));

constexpr int ISZ = 16, HSZ = 32, TT = 512, BB = 8192;
constexpr int LDS_STRIDE = 40;  // bf16 elems per h-plane row: 32 + pad

#define MFMA16(a, b, c) __builtin_amdgcn_mfma_f32_16x16x16bf16_1k((a), (b), (c), 0, 0, 0)

__device__ __forceinline__ float fsig(float x) {
  return __builtin_amdgcn_rcpf(1.0f + __builtin_amdgcn_exp2f(-1.44269504f * x));
}

// split fp32x4 -> hi/lo bf16x4 fragments (RNE split: v = hi + lo + O(2^-16 v))
__device__ __forceinline__ void split4(f4 v, short4v& hi, short4v& lo) {
  bf4 b1, b2;
#pragma unroll
  for (int i = 0; i < 4; ++i) b1[i] = (__bf16)v[i];
#pragma unroll
  for (int i = 0; i < 4; ++i) b2[i] = (__bf16)(v[i] - (float)b1[i]);
  hi = __builtin_bit_cast(short4v, b1);
  lo = __builtin_bit_cast(short4v, b2);
}

__global__ __launch_bounds__(512, 4) void lstm_mfma(
    const float* __restrict__ x, const float* __restrict__ W_ih,
    const float* __restrict__ W_hh, const float* __restrict__ b_ih,
    const float* __restrict__ b_hh, const float* __restrict__ W_fc,
    const float* __restrict__ b_fc, float* __restrict__ out) {
  // h planes: [buf][plane(h1/h2)][row 16][stride 40 bf16] = 5120 B
  __shared__ __align__(16) __bf16 hlds[2][2][16][LDS_STRIDE];
  // gate exchange: [gate][batch row][unit + pad] f32 = 8448 B
  __shared__ __align__(16) float gbuf[4][16][HSZ + 1];

  const int tid = threadIdx.x;
  const int wv = tid >> 6;       // wave 0..7
  const int g = wv & 3;          // gate index (i,f,g,o) of this wave's N-block
  const int uh = wv >> 2;        // unit half (0: units 0-15, 1: 16-31)
  const int L = tid & 63;
  const int m = L & 15;          // M index (row) for A/C; N index (col) for B
  const int q = L >> 4;          // quad
  const int row0 = blockIdx.x * 16;
  const int uw = uh * 16 + m;    // unit column of this wave's acc
  const int j = g * 32 + uw;     // gate row in the 4H dim

  // owned cell element: element id = wv*64 + L  ->  (batch row eR, unit eu)
  const int eR = wv * 2 + (L >> 5);  // 0..15
  const int eu = L & 31;             // 0..31

  // ---- load + split weights for this wave's single gate row (once) ----
  short4v whh1a, whh1b, whh2a, whh2b, wih1, wih2;
  f4 biasv;
  {
    f4 wa = *(const f4*)(W_hh + j * HSZ + q * 4);        // k = q*4..q*4+3
    f4 wb = *(const f4*)(W_hh + j * HSZ + 16 + q * 4);   // k = 16+q*4..
    split4(wa, whh1a, whh2a);
    split4(wb, whh1b, whh2b);
    f4 wi = *(const f4*)(W_ih + j * ISZ + q * 4);
    split4(wi, wih1, wih2);
    const float bb = b_ih[j] + b_hh[j];
    biasv = (f4){bb, bb, bb, bb};
  }

  // ---- zero h buffers (h_0 = 0) ----
  for (int i = tid; i < 2 * 2 * 16 * LDS_STRIDE; i += 512)
    ((__bf16*)hlds)[i] = (__bf16)0.0f;
  __syncthreads();

  float cst = 0.0f;  // cell state of the ONE owned element

  const float* xrow = x + (size_t)(row0 + m) * TT * ISZ + q * 4;
  f4 xc = *(const f4*)xrow;  // x fragment source for t=0

  for (int t = 0; t < TT; ++t) {
    const int p = t & 1;
    // A-fragments of h_t (issued first; latency hidden by TLP + x work)
    const short4v h1a = *(const short4v*)&hlds[p][0][m][q * 4];
    const short4v h1b = *(const short4v*)&hlds[p][0][m][16 + q * 4];
    const short4v h2a = *(const short4v*)&hlds[p][1][m][q * 4];
    const short4v h2b = *(const short4v*)&hlds[p][1][m][16 + q * 4];

    // prefetch next timestep's x
    const int tn = (t < TT - 1) ? t + 1 : t;
    const f4 xn = *(const f4*)(xrow + tn * ISZ);

    short4v x1, x2;
    split4(xc, x1, x2);

    // single accumulation chain, EXACT order of the 2-wave version
    f4 a = MFMA16(x1, wih1, biasv);
    a = MFMA16(x2, wih1, a);
    a = MFMA16(x1, wih2, a);
    a = MFMA16(h1a, whh1a, a);
    a = MFMA16(h1b, whh1b, a);
    a = MFMA16(h2a, whh1a, a);
    a = MFMA16(h2b, whh1b, a);
    a = MFMA16(h1a, whh2a, a);
    a = MFMA16(h1b, whh2b, a);
    xc = xn;

    // publish this wave's gate block: rows 4q+r, column uw
#pragma unroll
    for (int r = 0; r < 4; ++r) gbuf[g][q * 4 + r][uw] = a[r];
    __syncthreads();  // barrier 1: gbuf ready

    // gather all 4 gates of the owned element
    const float vi = gbuf[0][eR][eu];
    const float vf = gbuf[1][eR][eu];
    const float vg = gbuf[2][eR][eu];
    const float vo = gbuf[3][eR][eu];

    const float ig = fsig(vi);
    const float fg = fsig(vf);
    const float gv = 2.0f * fsig(2.0f * vg) - 1.0f;  // tanh(g)
    const float og = fsig(vo);
    float cc = fg * cst + ig * gv;
    cst = cc;
    const float th = 2.0f * fsig(2.0f * cc) - 1.0f;  // tanh(c)
    const float h = og * th;
    const __bf16 h1 = (__bf16)h;
    const __bf16 h2 = (__bf16)(h - (float)h1);
    hlds[p ^ 1][0][eR][eu] = h1;
    hlds[p ^ 1][1][eR][eu] = h2;
    __syncthreads();  // barrier 2: h_{t+1} planes ready; gbuf reads drained
  }

  // ---- epilogue: out[row] = sum_u h[row][u]*W_fc[u] + b_fc ----
  // final h (t=TT) is in buf[0] (TT even)
  if (tid < 16) {
    float s = b_fc[0];
#pragma unroll 8
    for (int uu = 0; uu < HSZ; ++uu) {
      const float h = (float)hlds[0][0][tid][uu] + (float)hlds[0][1][tid][uu];
      s += h * W_fc[uu];
    }
    out[row0 + tid] = s;
  }
}

extern "C" void kernel_launch(void* const* d_in, const int* in_sizes, int n_in,
                              void* d_out, int out_size, void* d_ws, size_t ws_size,
                              hipStream_t stream) {
  const float* x    = (const float*)d_in[0];
  const float* W_ih = (const float*)d_in[1];
  const float* W_hh = (const float*)d_in[2];
  const float* b_ih = (const float*)d_in[3];
  const float* b_hh = (const float*)d_in[4];
  const float* W_fc = (const float*)d_in[5];
  const float* b_fc = (const float*)d_in[6];
  float* out = (float*)d_out;

  dim3 grid(BB / 16);   // 512 blocks = 512 row-groups
  dim3 block(512);      // 8 waves per group (gate x unit-half split)
  lstm_mfma<<<grid, block, 0, stream>>>(x, W_ih, W_hh, b_ih, b_hh, W_fc, b_fc, out);
}

// Round 3
// 629.404 us; speedup vs baseline: 1.3576x; 1.0860x over previous
//
#include <hip/hip_runtime.h>

// LSTM I=16, H=32, B=8192, T=512, fp32 — MFMA version, 8-wave gate-split, K=32.
// (Resubmission of round-2 kernel: bench infra failed, no counter evidence
// against it; source re-audited for races/hangs/builtin types — clean.)
//
// Group = 16 batch rows, ONE block of 512 threads (8 waves).
// Wave wv computes ONE gate N-block: gate g = wv&3 (i,f,g,o), unit half
// uh = wv>>2. Gate pre-activations exchanged via LDS (gbuf); each lane then
// owns exactly ONE cell element (512 elems / 512 lanes).
//
// Changes vs round-1 (466 us dispatch, VALU 53% / Mfma 28% / cf 50M):
//  - native gfx950 v_mfma_f32_16x16x32_bf16: 5 MFMAs/wave-step instead of 9
//    (shorter dep chain, h fragments read as 2x ds_read_b128 not 4x b64)
//  - x split de-replicated: lanes 0-255 split x[t+1] into an LDS plane once;
//    waves read the packed A-fragment with one ds_read_b128 (kills the 8x
//    redundant split4 VALU work that dominated VALUBusy)
//  - bank-even LDS strides: h row [h1|h2] padded to 72 bf16 (stride 36 words:
//    b128 reads hit every bank exactly 8x = floor), x row padded to 40 bf16
//
// Precision: split-bf16. gates = (x1+x2)@W1 + (x1+x2)@W2 (ih, x2@W2 is a new
// bonus term vs round-1) + h1@W1 + h2@W1 + h1@W2 (hh; h2@W2 dropped as before).
// MFMA 16x16x32 bf16 fragment mapping (m89/m92-verified family):
//   A: lane(m=L&15, q=L>>4) holds A[m][k=8q+j], j=0..7 (contiguous k)
//   B: lane(n=L&15, q)      holds B[k=8q+j][n]
//   C/D: lane holds D[row=4q+reg][col=n]

typedef float f4 __attribute__((ext_vector_type(4)));
typedef __bf16 bf8v __attribute__((ext_vector_type(8)));

constexpr int ISZ = 16, HSZ = 32, TT = 512, BB = 8192;
constexpr int HSTR = 72;  // bf16/row: [h1(32)|h2(32)] + 8 pad -> 144B (16B mult)
constexpr int XSTR = 40;  // bf16/row: [x1(16)|x2(16)] + 8 pad -> 80B (16B mult)

#define MFMA32(a, b, c) __builtin_amdgcn_mfma_f32_16x16x32_bf16((a), (b), (c), 0, 0, 0)

__device__ __forceinline__ float fsig(float x) {
  return __builtin_amdgcn_rcpf(1.0f + __builtin_amdgcn_exp2f(-1.44269504f * x));
}

// split 8 fp32 -> hi/lo bf16 fragments (RNE split: v = hi + lo + O(2^-16 v))
__device__ __forceinline__ void split8(const float* v, bf8v& hi, bf8v& lo) {
#pragma unroll
  for (int i = 0; i < 8; ++i) {
    const __bf16 h = (__bf16)v[i];
    hi[i] = h;
    lo[i] = (__bf16)(v[i] - (float)h);
  }
}

__global__ __launch_bounds__(512, 4) void lstm_mfma(
    const float* __restrict__ x, const float* __restrict__ W_ih,
    const float* __restrict__ W_hh, const float* __restrict__ b_ih,
    const float* __restrict__ b_hh, const float* __restrict__ W_fc,
    const float* __restrict__ b_fc, float* __restrict__ out) {
  // h planes: [buf][row 16][72 bf16] = 4608 B (packed h1|h2, double-buffered)
  __shared__ __align__(16) __bf16 hl[2][16][HSTR];
  // x planes: [buf][row 16][40 bf16] = 2560 B (packed x1|x2, double-buffered)
  __shared__ __align__(16) __bf16 xs[2][16][XSTR];
  // gate exchange: [gate][batch row][unit + pad] f32 = 8448 B
  __shared__ __align__(16) float gbuf[4][16][HSZ + 1];

  const int tid = threadIdx.x;
  const int wv = tid >> 6;       // wave 0..7
  const int g = wv & 3;          // gate (i,f,g,o) of this wave's N-block
  const int uh = wv >> 2;        // unit half
  const int L = tid & 63;
  const int m = L & 15;          // M (batch row) for A/C; N (unit) for B
  const int q = L >> 4;          // quad
  const int row0 = blockIdx.x * 16;
  const int uw = uh * 16 + m;    // unit column of this wave's acc
  const int j = g * 32 + uw;     // gate row in the 4H dim

  // owned cell element
  const int eR = wv * 2 + (L >> 5);  // batch row 0..15
  const int eu = L & 31;             // unit 0..31

  // ---- load + split weights for this wave's gate row (once) ----
  bf8v bih1, bih2, bhh1, bhh2;
  f4 biasv;
  {
    float wh[8];
    *(f4*)&wh[0] = *(const f4*)(W_hh + j * HSZ + 8 * q);
    *(f4*)&wh[4] = *(const f4*)(W_hh + j * HSZ + 8 * q + 4);
    split8(wh, bhh1, bhh2);
    float wi[8];
    const int k8 = (q & 1) * 8;  // B rows k>=16 wrap to W_ih k-16
    *(f4*)&wi[0] = *(const f4*)(W_ih + j * ISZ + k8);
    *(f4*)&wi[4] = *(const f4*)(W_ih + j * ISZ + k8 + 4);
    split8(wi, bih1, bih2);
    const float bb = b_ih[j] + b_hh[j];
    biasv = (f4){bb, bb, bb, bb};
  }

  // ---- zero h buffers; stage split-x for t=0 ----
  for (int i = tid; i < 2 * 16 * HSTR; i += 512) ((__bf16*)hl)[i] = (__bf16)0.0f;
  const int xr = tid >> 4, xi = tid & 15;  // x staging duty (lanes 0..255)
  const float* xbase = x + (size_t)(row0 + xr) * TT * ISZ + xi;
  if (tid < 256) {
    const float v = xbase[0];
    const __bf16 h = (__bf16)v;
    xs[0][xr][xi] = h;
    xs[0][xr][16 + xi] = (__bf16)(v - (float)h);
  }
  __syncthreads();

  float cst = 0.0f;  // cell state of the ONE owned element

  for (int t = 0; t < TT; ++t) {
    const int p = t & 1;
    // packed A-fragments (one ds_read_b128 each, bank-even strides)
    const bf8v ax  = *(const bf8v*)&xs[p][m][8 * q];
    const bf8v ah1 = *(const bf8v*)&hl[p][m][8 * q];
    const bf8v ah2 = *(const bf8v*)&hl[p][m][32 + 8 * q];

    // prefetch next timestep's x (coalesced, one f32 per staging lane)
    float xnext = 0.0f;
    const int tn = (t < TT - 1) ? t + 1 : t;
    if (tid < 256) xnext = xbase[(size_t)tn * ISZ];

    // 5-deep K=32 accumulation chain
    f4 a = MFMA32(ax, bih1, biasv);  // x1@W1 + x2@W1
    a = MFMA32(ax, bih2, a);         // x1@W2 + x2@W2
    a = MFMA32(ah1, bhh1, a);        // h1@W1 (full K)
    a = MFMA32(ah2, bhh1, a);        // h2@W1
    a = MFMA32(ah1, bhh2, a);        // h1@W2

    // publish this wave's gate block: rows 4q+r, column uw
#pragma unroll
    for (int r = 0; r < 4; ++r) gbuf[g][q * 4 + r][uw] = a[r];
    __syncthreads();  // barrier 1: gbuf ready

    // gather all 4 gates of the owned element
    const float vi = gbuf[0][eR][eu];
    const float vf = gbuf[1][eR][eu];
    const float vg = gbuf[2][eR][eu];
    const float vo = gbuf[3][eR][eu];

    const float ig = fsig(vi);
    const float fg = fsig(vf);
    const float gv = 2.0f * fsig(2.0f * vg) - 1.0f;  // tanh(g)
    const float og = fsig(vo);
    const float cc = fg * cst + ig * gv;
    cst = cc;
    const float th = 2.0f * fsig(2.0f * cc) - 1.0f;  // tanh(c)
    const float h = og * th;
    const __bf16 h1 = (__bf16)h;
    hl[p ^ 1][eR][eu] = h1;
    hl[p ^ 1][eR][32 + eu] = (__bf16)(h - (float)h1);

    // stage split-x for t+1 (overlapped with cell update)
    if (tid < 256) {
      const __bf16 xh = (__bf16)xnext;
      xs[p ^ 1][xr][xi] = xh;
      xs[p ^ 1][xr][16 + xi] = (__bf16)(xnext - (float)xh);
    }
    __syncthreads();  // barrier 2: h_{t+1} + x_{t+1} ready; gbuf drained
  }

  // ---- epilogue: out[row] = sum_u h[row][u]*W_fc[u] + b_fc ----
  // final h (t=TT) is in buf[0] (TT even)
  if (tid < 16) {
    float s = b_fc[0];
#pragma unroll 8
    for (int uu = 0; uu < HSZ; ++uu) {
      const float h = (float)hl[0][tid][uu] + (float)hl[0][tid][32 + uu];
      s += h * W_fc[uu];
    }
    out[row0 + tid] = s;
  }
}

extern "C" void kernel_launch(void* const* d_in, const int* in_sizes, int n_in,
                              void* d_out, int out_size, void* d_ws, size_t ws_size,
                              hipStream_t stream) {
  const float* x    = (const float*)d_in[0];
  const float* W_ih = (const float*)d_in[1];
  const float* W_hh = (const float*)d_in[2];
  const float* b_ih = (const float*)d_in[3];
  const float* b_hh = (const float*)d_in[4];
  const float* W_fc = (const float*)d_in[5];
  const float* b_fc = (const float*)d_in[6];
  float* out = (float*)d_out;

  dim3 grid(BB / 16);   // 512 blocks = 512 row-groups
  dim3 block(512);      // 8 waves per group (gate x unit-half split)
  lstm_mfma<<<grid, block, 0, stream>>>(x, W_ih, W_hh, b_ih, b_hh, W_fc, b_fc, out);
}